// Round 12
// baseline (274.249 us; speedup 1.0000x reference)
//
#include <hip/hip_runtime.h>
#include <hip/hip_bf16.h>
#include <cstdint>

typedef unsigned short u16;
typedef __bf16 bf16x8 __attribute__((ext_vector_type(8)));
typedef float floatx4 __attribute__((ext_vector_type(4)));

#define AS1 __attribute__((address_space(1)))
#define AS3 __attribute__((address_space(3)))

#define SCHED0  __builtin_amdgcn_sched_barrier(0)
#define BARRIER __builtin_amdgcn_s_barrier()

// round-to-nearest-even f32 -> bf16 bits
static __device__ __forceinline__ u16 f2bf(float f) {
    union { float f; unsigned int u; } v; v.f = f;
    unsigned int u = v.u;
    return (u16)((u + 0x7FFFu + ((u >> 16) & 1u)) >> 16);
}

// LDS byte offset of a __shared__ address (AS3 pointers are 32-bit)
static __device__ __forceinline__ unsigned lds_off(const u16* p) {
    return (unsigned)(unsigned long long)(const AS3 u16*)p;
}
// inline-asm ds_read_b128; "=&v" early-clobber; manual counted lgkmcnt +
// SCHED0 order the consumers (rule #18).
static __device__ __forceinline__ bf16x8 ds_read8(unsigned off) {
    bf16x8 r;
    asm volatile("ds_read_b128 %0, %1" : "=&v"(r) : "v"(off));
    return r;
}

template <int N> __device__ __forceinline__ void wvm() {
    if constexpr (N == 0) asm volatile("s_waitcnt vmcnt(0)" ::: "memory");
    else if constexpr (N == 2) asm volatile("s_waitcnt vmcnt(2)" ::: "memory");
    else if constexpr (N == 3) asm volatile("s_waitcnt vmcnt(3)" ::: "memory");
    else if constexpr (N == 6) asm volatile("s_waitcnt vmcnt(6)" ::: "memory");
}
template <int N> __device__ __forceinline__ void wlg() {
    if constexpr (N == 0) asm volatile("s_waitcnt lgkmcnt(0)" ::: "memory");
    else if constexpr (N == 4) asm volatile("s_waitcnt lgkmcnt(4)" ::: "memory");
    else if constexpr (N == 8) asm volatile("s_waitcnt lgkmcnt(8)" ::: "memory");
}

// ---------------------------------------------------------------------------
// R18 prep: BALANCED transpose tiles 128 rows x 64 cols f32 (was 128x32).
// Read segments 256B (4 rows/wave x 64 f32), write segments 256B (one
// out-row slice per wave as 64 x ushort2). LDS [128][65] pad -> readback
// tile[2*ln][c],tile[2*ln+1][c] is 2-way bank aliasing (free, m136).
// Grid: [0,512) w1-T (bx 0..63, by 0..7), [512,1024) w2-T (bx 0..15,
// by 0..31), [1024,9216) LayerNorm rows. LN body unchanged (passed R0-R17).
// ---------------------------------------------------------------------------
__device__ __forceinline__ void transpose_body(
    const float* __restrict__ in, u16* __restrict__ out,
    int R, int Ccols, int bx, int by, int tid, float (*tile)[65])
{
    const int r0 = by * 128, c0 = bx * 64;
#pragma unroll
    for (int p = 0; p < 8; ++p) {
        const int f = p * 256 + tid;          // 0..2047 float4s
        const int r = f >> 4, c4 = (f & 15) * 4;
        const float4 v = *(const float4*)&in[(size_t)(r0 + r) * Ccols + c0 + c4];
        tile[r][c4 + 0] = v.x; tile[r][c4 + 1] = v.y;
        tile[r][c4 + 2] = v.z; tile[r][c4 + 3] = v.w;
    }
    __syncthreads();
    const int wv = tid >> 6, ln = tid & 63;
#pragma unroll
    for (int i = 0; i < 16; ++i) {
        const int c = i * 4 + wv;             // out-row (input col) 0..63
        ushort2 o = { f2bf(tile[ln * 2][c]), f2bf(tile[ln * 2 + 1][c]) };
        *(ushort2*)&out[(size_t)(c0 + c) * R + r0 + ln * 2] = o;
    }
}

__global__ __launch_bounds__(256)
void prep(const float* __restrict__ w1, const float* __restrict__ w2,
          const float* __restrict__ act, const float* __restrict__ ln_scale,
          const float* __restrict__ ln_bias,
          u16* __restrict__ W1t, u16* __restrict__ W2t, u16* __restrict__ X)
{
    __shared__ float tile[128][65];   // 33.3KB; LN reuses first 8 floats
    const int id  = blockIdx.x;
    const int tid = threadIdx.x;

    if (id < 512) {           // w1 [1024][4096] -> W1t [4096][1024]
        transpose_body(w1, W1t, 1024, 4096, id & 63, id >> 6, tid, tile);
        return;
    }
    if (id < 1024) {          // w2 [4096][1024] -> W2t [1024][4096]
        const int t = id - 512;
        transpose_body(w2, W2t, 4096, 1024, t & 15, t >> 4, tid, tile);
        return;
    }
    // LayerNorm, one block per row
    const int row = id - 1024;
    const float4 v = ((const float4*)(act + (size_t)row * 1024))[tid];
    float s  = v.x + v.y + v.z + v.w;
    float ss = v.x * v.x + v.y * v.y + v.z * v.z + v.w * v.w;
#pragma unroll
    for (int off = 32; off > 0; off >>= 1) {
        s  += __shfl_xor(s, off, 64);
        ss += __shfl_xor(ss, off, 64);
    }
    float* red = &tile[0][0];
    const int wave = tid >> 6, lane = tid & 63;
    if (lane == 0) { red[wave] = s; red[4 + wave] = ss; }
    __syncthreads();
    s  = red[0] + red[1] + red[2] + red[3];
    ss = red[4] + red[5] + red[6] + red[7];
    const float mu  = s * (1.0f / 1024.0f);
    const float var = ss * (1.0f / 1024.0f) - mu * mu;
    const float rs  = rsqrtf(var + 1e-5f);
    const float4 sc = ((const float4*)ln_scale)[tid];
    const float4 bi = ((const float4*)ln_bias)[tid];
    ushort4 o;
    o.x = f2bf((v.x - mu) * rs * sc.x + bi.x);
    o.y = f2bf((v.y - mu) * rs * sc.y + bi.y);
    o.z = f2bf((v.z - mu) * rs * sc.z + bi.z);
    o.w = f2bf((v.w - mu) * rs * sc.w + bi.w);
    ((ushort4*)(X + (size_t)row * 1024))[tid] = o;
}

// ---------------------------------------------------------------------------
// R18 GEMM1 (= R11 gemm1, best proven 77us, + XCD-locked panel mapping):
// H = relu(X @ W1t^T + b1), bf16.  M=8192 N=4096 K=1024.
// BM=BN=256, BK=64, 8 waves (2M x 4N), wave tile 128x64, acc[8][4].
// 4 phases/K-tile; cross-phase read-ahead (p0 reads B(8)+Ap0(4)+Ap1(4);
// p1 reads Ap2; p2 reads Ap3; p3 none); counted lgkm (4/4/4/0); ONE
// barrier per phase; staging order [A0,A2|B0,B1|B2,B3|A1,A3]; vmcnt(2)
// at p0-end and p3-end (ledger in R11, unchanged).
//
// XCD mapping (T1; fixes FETCH 49MB vs 24MB compulsory): dispatcher
// round-robins blocks to XCDs (orig%8). Give each XCD ONE B panel per
// round: xcd = orig&7, j = orig>>3 (0..63 over 2 rounds);
// bm = j&31, bn = 2*xcd + (j>>5). XCD keeps its 512KB B panel L2-hot;
// A panels stream via L3. Pure index remap; schedule untouched.
// ---------------------------------------------------------------------------
__global__ __launch_bounds__(512, 2)
void gemm1(const u16* __restrict__ A, const u16* __restrict__ Bt,
           const float* __restrict__ bias, u16* __restrict__ H)
{
    constexpr int K = 1024, N = 4096;
    constexpr int ASZ = 256 * 64;        // u16 per buffer (32KB)
    __shared__ __align__(16) u16 Alds[2 * ASZ];
    __shared__ __align__(16) u16 Blds[2 * ASZ];

    const int tid  = threadIdx.x;
    const int wave = tid >> 6;
    const int lane = tid & 63;
    const int srow = lane >> 3;
    const int sst  = lane & 7;
    const int quad = lane >> 4;
    const int l16  = lane & 15;
    const int rkey = l16 & 7;
    const int wm   = wave >> 2;          // 0..1
    const int wn   = wave & 3;           // 0..3

    const int orig = blockIdx.x;
    const int xcd  = orig & 7;
    const int j    = orig >> 3;          // 0..63
    const int bm   = j & 31;
    const int bn   = 2 * xcd + (j >> 5); // XCD-locked B panel

    const u16* Ag = A  + (size_t)bm * 256 * K;
    const u16* Bg = Bt + (size_t)bn * 256 * K;

    auto stA = [&](int buf, int c, int k0) {
        const int row = c * 64 + wave * 8 + srow;
        const int col = (sst ^ (row & 7)) * 8;
        __builtin_amdgcn_global_load_lds(
            (AS1 void*)(Ag + (size_t)row * K + k0 + col),
            (AS3 void*)(&Alds[buf * ASZ + c * 4096 + wave * 512]), 16, 0, 0);
    };
    auto stB = [&](int buf, int c, int k0) {
        const int row = c * 64 + wave * 8 + srow;
        const int col = (sst ^ (row & 7)) * 8;
        __builtin_amdgcn_global_load_lds(
            (AS1 void*)(Bg + (size_t)row * K + k0 + col),
            (AS3 void*)(&Blds[buf * ASZ + c * 4096 + wave * 512]), 16, 0, 0);
    };

    const unsigned Ab = lds_off(&Alds[0]);
    const unsigned Bb = lds_off(&Blds[0]);
    unsigned aoff[8][2], boff[4][2];
#pragma unroll
    for (int mi = 0; mi < 8; ++mi)
#pragma unroll
        for (int kh = 0; kh < 2; ++kh)
            aoff[mi][kh] = ((wm * 128 + mi * 16 + l16) * 64 +
                            ((kh * 4 + quad) ^ rkey) * 8) * 2;
#pragma unroll
    for (int ni = 0; ni < 4; ++ni)
#pragma unroll
        for (int kh = 0; kh < 2; ++kh)
            boff[ni][kh] = ((wn * 64 + ni * 16 + l16) * 64 +
                            ((kh * 4 + quad) ^ rkey) * 8) * 2;

    floatx4 acc[8][4];
#pragma unroll
    for (int i = 0; i < 8; ++i)
#pragma unroll
        for (int jj = 0; jj < 4; ++jj)
            acc[i][jj] = (floatx4){0.f, 0.f, 0.f, 0.f};

    constexpr int NT = K / 64;           // 16

    // prologue: tile0 -> buf0, consumption order; keep A1A3 in flight
    stA(0, 0, 0); stA(0, 2, 0);
    stB(0, 0, 0); stB(0, 1, 0); stB(0, 2, 0); stB(0, 3, 0);
    stA(0, 1, 0); stA(0, 3, 0);
    wvm<2>();
    SCHED0; BARRIER; SCHED0;

    bf16x8 bres[4][2];
    bf16x8 afr[2][2][2];                 // [slot][j][kh]
    for (int t = 0; t < NT; ++t) {
        const unsigned ab = Ab + (unsigned)((t & 1) * ASZ * 2);
        const unsigned bb = Bb + (unsigned)((t & 1) * ASZ * 2);
        const int nb = (t + 1) & 1;
        const int k1 = (t + 1) * 64;
        const bool st = (t + 1 < NT);

#pragma unroll
        for (int p = 0; p < 4; ++p) {
            // ---- reads (read-ahead by one phase) ----
            if (p == 0) {
#pragma unroll
                for (int ni = 0; ni < 4; ++ni)
#pragma unroll
                    for (int kh = 0; kh < 2; ++kh)
                        bres[ni][kh] = ds_read8(bb + boff[ni][kh]);
#pragma unroll
                for (int sl = 0; sl < 2; ++sl)
#pragma unroll
                    for (int jj = 0; jj < 2; ++jj)
#pragma unroll
                        for (int kh = 0; kh < 2; ++kh)
                            afr[sl][jj][kh] = ds_read8(ab + aoff[sl * 2 + jj][kh]);
            } else if (p < 3) {
#pragma unroll
                for (int jj = 0; jj < 2; ++jj)
#pragma unroll
                    for (int kh = 0; kh < 2; ++kh)
                        afr[(p + 1) & 1][jj][kh] =
                            ds_read8(ab + aoff[(p + 1) * 2 + jj][kh]);
            }
            // ---- stage next tile ----
            if (st) {
                if (p == 0)      { stA(nb, 0, k1); stA(nb, 2, k1); }
                else if (p == 1) { stB(nb, 0, k1); stB(nb, 1, k1); }
                else if (p == 2) { stB(nb, 2, k1); stB(nb, 3, k1); }
                else             { stA(nb, 1, k1); stA(nb, 3, k1); }
            }
            // ---- counted lgkm wait for the frags THIS phase consumes ----
            if (p == 3) wlg<0>(); else wlg<4>();
            SCHED0;
            __builtin_amdgcn_s_setprio(1);
#pragma unroll
            for (int kh = 0; kh < 2; ++kh)
#pragma unroll
                for (int jj = 0; jj < 2; ++jj)
#pragma unroll
                    for (int ni = 0; ni < 4; ++ni)
                        acc[2 * p + jj][ni] = __builtin_amdgcn_mfma_f32_16x16x32_bf16(
                            bres[ni][kh], afr[p & 1][jj][kh], acc[2 * p + jj][ni], 0, 0, 0);
            __builtin_amdgcn_s_setprio(0);
            SCHED0;
            // ---- counted vmcnt (R11 ledger) ----
            if (p == 0) {
                if (st) wvm<2>(); else wvm<0>();
            }
            if (p == 3 && st) wvm<2>();
            BARRIER; SCHED0;
        }
    }

    // epilogue: bf16 + bias + relu
    const int mbase = bm * 256 + wm * 128;
    const int nbase = bn * 256 + wn * 64;
#pragma unroll
    for (int mi = 0; mi < 8; ++mi) {
        const int m = mbase + mi * 16 + l16;
#pragma unroll
        for (int ni = 0; ni < 4; ++ni) {
            const int n0 = nbase + ni * 16 + quad * 4;
            const float4 bv = *(const float4*)&bias[n0];
            float v0 = fmaxf(acc[mi][ni][0] + bv.x, 0.f);
            float v1 = fmaxf(acc[mi][ni][1] + bv.y, 0.f);
            float v2 = fmaxf(acc[mi][ni][2] + bv.z, 0.f);
            float v3 = fmaxf(acc[mi][ni][3] + bv.w, 0.f);
            ushort4 o = { f2bf(v0), f2bf(v1), f2bf(v2), f2bf(v3) };
            *(ushort4*)&H[(size_t)m * N + n0] = o;
        }
    }
}

// ---------------------------------------------------------------------------
// R18 GEMM2 (= R11 gemm2, proven, + XCD-locked panel mapping): out =
// H @ W2t^T + b2, fp32. M=8192 N=1024 K=4096. BM=256 BN=128, grid 256 =
// 1/CU, 8 waves (4M x 2N), wave 64x64. Triple-buffered kh-split LDS;
// cross-tile frag read-ahead; staging 2 tiles ahead; uniform
// vmcnt(6)/lgkmcnt(8); one barrier per phase.
// XCD mapping: bn = orig&7 = XCD id (1MB W2t panel L2-resident per XCD),
// bm = orig>>3. Pure index remap.
// ---------------------------------------------------------------------------
__global__ __launch_bounds__(512, 2)
void gemm2(const u16* __restrict__ A, const u16* __restrict__ Bt,
           const float* __restrict__ bias, float* __restrict__ Cout)
{
    constexpr int K = 4096, N = 1024;
    constexpr int ASZ = 2 * 256 * 32;    // u16 per buffer (32KB)
    constexpr int BSZ = 2 * 128 * 32;    // u16 per buffer (16KB)
    __shared__ __align__(16) u16 Alds[3 * ASZ];   // 96KB
    __shared__ __align__(16) u16 Blds[3 * BSZ];   // 48KB

    const int tid  = threadIdx.x;
    const int wave = tid >> 6;
    const int lane = tid & 63;
    const int quad = lane >> 4;
    const int l16  = lane & 15;
    const int key4 = (l16 >> 1) & 3;
    const int wm   = wave >> 1;          // 0..3
    const int wn   = wave & 1;           // 0..1

    const int orig = blockIdx.x;
    const int bn   = orig & 7;           // = XCD id -> panel L2-locked
    const int bm   = orig >> 3;          // 0..31

    const u16* Ag = A  + (size_t)bm * 256 * K;
    const u16* Bg = Bt + (size_t)bn * 128 * K;

    auto stA = [&](int buf, int kh, int c, int k0) {
        const int row = c * 128 + wave * 16 + (lane >> 2);
        const int col = kh * 32 + ((lane & 3) ^ ((row >> 1) & 3)) * 8;
        __builtin_amdgcn_global_load_lds(
            (AS1 void*)(Ag + (size_t)row * K + k0 + col),
            (AS3 void*)(&Alds[buf * ASZ + kh * 8192 + c * 4096 + wave * 512]),
            16, 0, 0);
    };
    auto stB = [&](int buf, int kh, int k0) {
        const int row = wave * 16 + (lane >> 2);
        const int col = kh * 32 + ((lane & 3) ^ ((row >> 1) & 3)) * 8;
        __builtin_amdgcn_global_load_lds(
            (AS1 void*)(Bg + (size_t)row * K + k0 + col),
            (AS3 void*)(&Blds[buf * BSZ + kh * 4096 + wave * 512]), 16, 0, 0);
    };

    const unsigned Ab = lds_off(&Alds[0]);
    const unsigned Bb = lds_off(&Blds[0]);
    unsigned aoff[4], boff[4];
#pragma unroll
    for (int mi = 0; mi < 4; ++mi)
        aoff[mi] = ((wm * 64 + mi * 16 + l16) * 32 + (quad ^ key4) * 8) * 2;
#pragma unroll
    for (int ni = 0; ni < 4; ++ni)
        boff[ni] = ((wn * 64 + ni * 16 + l16) * 32 + (quad ^ key4) * 8) * 2;

    floatx4 acc[4][4];
#pragma unroll
    for (int i = 0; i < 4; ++i)
#pragma unroll
        for (int j = 0; j < 4; ++j)
            acc[i][j] = (floatx4){0.f, 0.f, 0.f, 0.f};

    constexpr int NT = K / 64;           // 64

    stA(0, 0, 0, 0);  stA(0, 0, 1, 0);  stB(0, 0, 0);
    stA(0, 1, 0, 0);  stA(0, 1, 1, 0);  stB(0, 1, 0);
    stA(1, 0, 0, 64); stA(1, 0, 1, 64); stB(1, 0, 64);
    stA(1, 1, 0, 64); stA(1, 1, 1, 64); stB(1, 1, 64);
    wvm<6>();
    SCHED0; BARRIER; SCHED0;

    bf16x8 fa[2][4], fb[2][4];
#pragma unroll
    for (int i = 0; i < 4; ++i) {
        fa[0][i] = ds_read8(Ab + aoff[i]);
        fb[0][i] = ds_read8(Bb + boff[i]);
    }

    int bs0 = 0, bs1 = 1, bs2 = 2;
    for (int t = 0; t < NT; ++t) {
        const int k2 = (t + 2) * 64;
        const bool st  = (t + 2 < NT);
        const bool rd1 = (t + 1 < NT);
        const unsigned a0 = Ab + (unsigned)(bs0 * ASZ * 2);
        const unsigned b0 = Bb + (unsigned)(bs0 * BSZ * 2);
        const unsigned a1 = Ab + (unsigned)(bs1 * ASZ * 2);
        const unsigned b1 = Bb + (unsigned)(bs1 * BSZ * 2);

        // phase kh=0
#pragma unroll
        for (int i = 0; i < 4; ++i) {
            fa[1][i] = ds_read8(a0 + 16384u + aoff[i]);
            fb[1][i] = ds_read8(b0 + 8192u  + boff[i]);
        }
        if (st) { stA(bs2, 0, 0, k2); stA(bs2, 0, 1, k2); stB(bs2, 0, k2); }
        wlg<8>();
        SCHED0;
        __builtin_amdgcn_s_setprio(1);
#pragma unroll
        for (int mi = 0; mi < 4; ++mi)
#pragma unroll
            for (int ni = 0; ni < 4; ++ni)
                acc[mi][ni] = __builtin_amdgcn_mfma_f32_16x16x32_bf16(
                    fb[0][ni], fa[0][mi], acc[mi][ni], 0, 0, 0);
        __builtin_amdgcn_s_setprio(0);
        SCHED0;
        if (st)       wvm<6>();
        else if (rd1) wvm<3>();
        BARRIER; SCHED0;

        // phase kh=1
        if (rd1) {
#pragma unroll
            for (int i = 0; i < 4; ++i) {
                fa[0][i] = ds_read8(a1 + aoff[i]);
                fb[0][i] = ds_read8(b1 + boff[i]);
            }
        }
        if (st) { stA(bs2, 1, 0, k2); stA(bs2, 1, 1, k2); stB(bs2, 1, k2); }
        if (rd1) wlg<8>(); else wlg<0>();
        SCHED0;
        __builtin_amdgcn_s_setprio(1);
#pragma unroll
        for (int mi = 0; mi < 4; ++mi)
#pragma unroll
            for (int ni = 0; ni < 4; ++ni)
                acc[mi][ni] = __builtin_amdgcn_mfma_f32_16x16x32_bf16(
                    fb[1][ni], fa[1][mi], acc[mi][ni], 0, 0, 0);
        __builtin_amdgcn_s_setprio(0);
        SCHED0;
        if (st)       wvm<6>();
        else if (rd1) wvm<0>();
        BARRIER; SCHED0;

        const int tmp = bs0; bs0 = bs1; bs1 = bs2; bs2 = tmp;
    }

    const int mbase = bm * 256 + wm * 64;
    const int nbase = bn * 128 + wn * 64;
#pragma unroll
    for (int mi = 0; mi < 4; ++mi) {
        const int m = mbase + mi * 16 + l16;
#pragma unroll
        for (int ni = 0; ni < 4; ++ni) {
            const int n0 = nbase + ni * 16 + quad * 4;
            const float4 bv = *(const float4*)&bias[n0];
            float4 o = { acc[mi][ni][0] + bv.x, acc[mi][ni][1] + bv.y,
                         acc[mi][ni][2] + bv.z, acc[mi][ni][3] + bv.w };
            *(float4*)&Cout[(size_t)m * N + n0] = o;
        }
    }
}

// ---------------------------------------------------------------------------
// inputs: 0 act(4,2048,1024) f32, 1 mask(unused), 2 ln_scale(1024),
//         3 ln_bias(1024), 4 w1(1024,4096), 5 b1(4096), 6 w2(4096,1024),
//         7 b2(1024). out: (4,2048,1024) f32.
// ws (bf16 bits): X[8192*1024] | W1t[4096*1024] | W2t[1024*4096] | H[8192*4096]
// ---------------------------------------------------------------------------
extern "C" void kernel_launch(void* const* d_in, const int* in_sizes, int n_in,
                              void* d_out, int out_size, void* d_ws, size_t ws_size,
                              hipStream_t stream)
{
    const float* act      = (const float*)d_in[0];
    const float* ln_scale = (const float*)d_in[2];
    const float* ln_bias  = (const float*)d_in[3];
    const float* w1       = (const float*)d_in[4];
    const float* b1       = (const float*)d_in[5];
    const float* w2       = (const float*)d_in[6];
    const float* b2       = (const float*)d_in[7];
    float* out = (float*)d_out;

    const int M = 8192, C = 1024, CI = 4096;

    u16* X   = (u16*)d_ws;                 // [M][C]
    u16* W1t = X   + (size_t)M * C;        // [CI][C]
    u16* W2t = W1t + (size_t)CI * C;       // [C][CI]
    u16* H   = W2t + (size_t)C * CI;       // [M][CI]

    // prep: balanced 128x64 transpose tiles + LN (9216 blocks)
    prep<<<9216, 256, 0, stream>>>(w1, w2, act, ln_scale, ln_bias, W1t, W2t, X);
    // H = relu(X @ W1 + b1): R11 schedule + XCD-locked B panels
    gemm1<<<(M / 256) * (CI / 256), 512, 0, stream>>>(X, W1t, b1, H);
    // out = H @ W2 + b2: R11 schedule + XCD-locked B panels
    gemm2<<<(M / 256) * (C / 128), 512, 0, stream>>>(H, W2t, b2, out);
}

// Round 14
// 252.874 us; speedup vs baseline: 1.0845x; 1.0845x over previous
//
#include <hip/hip_runtime.h>
#include <hip/hip_bf16.h>
#include <cstdint>

typedef unsigned short u16;
typedef __bf16 bf16x8 __attribute__((ext_vector_type(8)));
typedef float floatx4 __attribute__((ext_vector_type(4)));

#define AS1 __attribute__((address_space(1)))
#define AS3 __attribute__((address_space(3)))

#define SCHED0  __builtin_amdgcn_sched_barrier(0)
#define BARRIER __builtin_amdgcn_s_barrier()

// round-to-nearest-even f32 -> bf16 bits
static __device__ __forceinline__ u16 f2bf(float f) {
    union { float f; unsigned int u; } v; v.f = f;
    unsigned int u = v.u;
    return (u16)((u + 0x7FFFu + ((u >> 16) & 1u)) >> 16);
}

// LDS byte offset of a __shared__ address (AS3 pointers are 32-bit)
static __device__ __forceinline__ unsigned lds_off(const u16* p) {
    return (unsigned)(unsigned long long)(const AS3 u16*)p;
}
// inline-asm ds_read_b128; "=&v" early-clobber; manual counted lgkmcnt +
// SCHED0 order the consumers (rule #18).
static __device__ __forceinline__ bf16x8 ds_read8(unsigned off) {
    bf16x8 r;
    asm volatile("ds_read_b128 %0, %1" : "=&v"(r) : "v"(off));
    return r;
}

template <int N> __device__ __forceinline__ void wvm() {
    if constexpr (N == 0) asm volatile("s_waitcnt vmcnt(0)" ::: "memory");
    else if constexpr (N == 2) asm volatile("s_waitcnt vmcnt(2)" ::: "memory");
    else if constexpr (N == 3) asm volatile("s_waitcnt vmcnt(3)" ::: "memory");
    else if constexpr (N == 6) asm volatile("s_waitcnt vmcnt(6)" ::: "memory");
}
template <int N> __device__ __forceinline__ void wlg() {
    if constexpr (N == 0) asm volatile("s_waitcnt lgkmcnt(0)" ::: "memory");
    else if constexpr (N == 4) asm volatile("s_waitcnt lgkmcnt(4)" ::: "memory");
    else if constexpr (N == 8) asm volatile("s_waitcnt lgkmcnt(8)" ::: "memory");
}

// ---------------------------------------------------------------------------
// R20 prep (= R19 with the LN coverage bug fixed):
//  [0,512)    : w1-T  (128x64 f32 tiles; 256B read AND write segments)
//  [512,1024) : w2-T
//  [1024,3072): LayerNorm, ONE WAVE PER ROW. R19 BUG: 64 lanes x 1 float4
//               = 256 of 1024 floats covered -> absmax 4.43. FIX: each lane
//               processes 4 float4s at [lane + 64*i] (coalesced 64-lane
//               segments), reduce over all 16 values, 4 ushort4 writes.
//               Still no LDS, no __syncthreads; 4 rows/block.
// ---------------------------------------------------------------------------
__device__ __forceinline__ void transpose_body(
    const float* __restrict__ in, u16* __restrict__ out,
    int R, int Ccols, int bx, int by, int tid, float (*tile)[65])
{
    const int r0 = by * 128, c0 = bx * 64;
#pragma unroll
    for (int p = 0; p < 8; ++p) {
        const int f = p * 256 + tid;          // 0..2047 float4s
        const int r = f >> 4, c4 = (f & 15) * 4;
        const float4 v = *(const float4*)&in[(size_t)(r0 + r) * Ccols + c0 + c4];
        tile[r][c4 + 0] = v.x; tile[r][c4 + 1] = v.y;
        tile[r][c4 + 2] = v.z; tile[r][c4 + 3] = v.w;
    }
    __syncthreads();
    const int wv = tid >> 6, ln = tid & 63;
#pragma unroll
    for (int i = 0; i < 16; ++i) {
        const int c = i * 4 + wv;             // out-row (input col) 0..63
        ushort2 o = { f2bf(tile[ln * 2][c]), f2bf(tile[ln * 2 + 1][c]) };
        *(ushort2*)&out[(size_t)(c0 + c) * R + r0 + ln * 2] = o;
    }
}

__global__ __launch_bounds__(256)
void prep(const float* __restrict__ w1, const float* __restrict__ w2,
          const float* __restrict__ act, const float* __restrict__ ln_scale,
          const float* __restrict__ ln_bias,
          u16* __restrict__ W1t, u16* __restrict__ W2t, u16* __restrict__ X)
{
    __shared__ float tile[128][65];   // 33.3KB (transpose blocks only)
    const int id  = blockIdx.x;
    const int tid = threadIdx.x;

    if (id < 512) {           // w1 [1024][4096] -> W1t [4096][1024]
        transpose_body(w1, W1t, 1024, 4096, id & 63, id >> 6, tid, tile);
        return;
    }
    if (id < 1024) {          // w2 [4096][1024] -> W2t [1024][4096]
        const int t = id - 512;
        transpose_body(w2, W2t, 4096, 1024, t & 15, t >> 4, tid, tile);
        return;
    }
    // LayerNorm: one wave per row, 4 rows per block. No LDS, no barriers.
    const int row  = (id - 1024) * 4 + (tid >> 6);
    const int lane = tid & 63;
    const float4* rowp = (const float4*)(act + (size_t)row * 1024);
    float4 v[4];
#pragma unroll
    for (int i = 0; i < 4; ++i) v[i] = rowp[lane + 64 * i];
    float s = 0.f, ss = 0.f;
#pragma unroll
    for (int i = 0; i < 4; ++i) {
        s  += v[i].x + v[i].y + v[i].z + v[i].w;
        ss += v[i].x * v[i].x + v[i].y * v[i].y
            + v[i].z * v[i].z + v[i].w * v[i].w;
    }
#pragma unroll
    for (int off = 32; off > 0; off >>= 1) {
        s  += __shfl_xor(s, off, 64);
        ss += __shfl_xor(ss, off, 64);
    }
    const float mu  = s * (1.0f / 1024.0f);
    const float var = ss * (1.0f / 1024.0f) - mu * mu;
    const float rs  = rsqrtf(var + 1e-5f);
    ushort4* xp = (ushort4*)(X + (size_t)row * 1024);
#pragma unroll
    for (int i = 0; i < 4; ++i) {
        const float4 sc = ((const float4*)ln_scale)[lane + 64 * i];
        const float4 bi = ((const float4*)ln_bias)[lane + 64 * i];
        ushort4 o;
        o.x = f2bf((v[i].x - mu) * rs * sc.x + bi.x);
        o.y = f2bf((v[i].y - mu) * rs * sc.y + bi.y);
        o.z = f2bf((v[i].z - mu) * rs * sc.z + bi.z);
        o.w = f2bf((v[i].w - mu) * rs * sc.w + bi.w);
        xp[lane + 64 * i] = o;
    }
}

// ---------------------------------------------------------------------------
// R20 GEMM1 (= R11 gemm1 verbatim, best proven 77.3us; bm-fastest map is
// XCD-optimal for A panels -- R5/R18 both proved remaps regress):
// H = relu(X @ W1t^T + b1), bf16.  M=8192 N=4096 K=1024.
// BM=BN=256, BK=64, 8 waves (2M x 4N), wave tile 128x64, acc[8][4].
// 4 phases/K-tile; cross-phase read-ahead (p0 reads B(8)+Ap0(4)+Ap1(4);
// p1 reads Ap2; p2 reads Ap3; p3 none); counted lgkm (4/4/4/0); ONE
// barrier per phase; staging order [A0,A2|B0,B1|B2,B3|A1,A3]; vmcnt(2)
// at p0-end and p3-end. Swizzle: store slot s^(row&7), read slot
// (kh*4+quad)^(l16&7) (0-conflict).
// ---------------------------------------------------------------------------
__global__ __launch_bounds__(512, 2)
void gemm1(const u16* __restrict__ A, const u16* __restrict__ Bt,
           const float* __restrict__ bias, u16* __restrict__ H)
{
    constexpr int K = 1024, N = 4096;
    constexpr int ASZ = 256 * 64;        // u16 per buffer (32KB)
    __shared__ __align__(16) u16 Alds[2 * ASZ];
    __shared__ __align__(16) u16 Blds[2 * ASZ];

    const int tid  = threadIdx.x;
    const int wave = tid >> 6;
    const int lane = tid & 63;
    const int srow = lane >> 3;
    const int sst  = lane & 7;
    const int quad = lane >> 4;
    const int l16  = lane & 15;
    const int rkey = l16 & 7;
    const int wm   = wave >> 2;          // 0..1
    const int wn   = wave & 3;           // 0..3

    const int id = blockIdx.x;
    const int bm = id & 31;              // bm-fastest (XCD-optimal, R5/R18)
    const int bn = id >> 5;              // 0..15

    const u16* Ag = A  + (size_t)bm * 256 * K;
    const u16* Bg = Bt + (size_t)bn * 256 * K;

    auto stA = [&](int buf, int c, int k0) {
        const int row = c * 64 + wave * 8 + srow;
        const int col = (sst ^ (row & 7)) * 8;
        __builtin_amdgcn_global_load_lds(
            (AS1 void*)(Ag + (size_t)row * K + k0 + col),
            (AS3 void*)(&Alds[buf * ASZ + c * 4096 + wave * 512]), 16, 0, 0);
    };
    auto stB = [&](int buf, int c, int k0) {
        const int row = c * 64 + wave * 8 + srow;
        const int col = (sst ^ (row & 7)) * 8;
        __builtin_amdgcn_global_load_lds(
            (AS1 void*)(Bg + (size_t)row * K + k0 + col),
            (AS3 void*)(&Blds[buf * ASZ + c * 4096 + wave * 512]), 16, 0, 0);
    };

    const unsigned Ab = lds_off(&Alds[0]);
    const unsigned Bb = lds_off(&Blds[0]);
    unsigned aoff[8][2], boff[4][2];
#pragma unroll
    for (int mi = 0; mi < 8; ++mi)
#pragma unroll
        for (int kh = 0; kh < 2; ++kh)
            aoff[mi][kh] = ((wm * 128 + mi * 16 + l16) * 64 +
                            ((kh * 4 + quad) ^ rkey) * 8) * 2;
#pragma unroll
    for (int ni = 0; ni < 4; ++ni)
#pragma unroll
        for (int kh = 0; kh < 2; ++kh)
            boff[ni][kh] = ((wn * 64 + ni * 16 + l16) * 64 +
                            ((kh * 4 + quad) ^ rkey) * 8) * 2;

    floatx4 acc[8][4];
#pragma unroll
    for (int i = 0; i < 8; ++i)
#pragma unroll
        for (int jj = 0; jj < 4; ++jj)
            acc[i][jj] = (floatx4){0.f, 0.f, 0.f, 0.f};

    constexpr int NT = K / 64;           // 16

    // prologue: tile0 -> buf0, consumption order; keep A1A3 in flight
    stA(0, 0, 0); stA(0, 2, 0);
    stB(0, 0, 0); stB(0, 1, 0); stB(0, 2, 0); stB(0, 3, 0);
    stA(0, 1, 0); stA(0, 3, 0);
    wvm<2>();
    SCHED0; BARRIER; SCHED0;

    bf16x8 bres[4][2];
    bf16x8 afr[2][2][2];                 // [slot][j][kh]
    for (int t = 0; t < NT; ++t) {
        const unsigned ab = Ab + (unsigned)((t & 1) * ASZ * 2);
        const unsigned bb = Bb + (unsigned)((t & 1) * ASZ * 2);
        const int nb = (t + 1) & 1;
        const int k1 = (t + 1) * 64;
        const bool st = (t + 1 < NT);

#pragma unroll
        for (int p = 0; p < 4; ++p) {
            // ---- reads (read-ahead by one phase) ----
            if (p == 0) {
#pragma unroll
                for (int ni = 0; ni < 4; ++ni)
#pragma unroll
                    for (int kh = 0; kh < 2; ++kh)
                        bres[ni][kh] = ds_read8(bb + boff[ni][kh]);
#pragma unroll
                for (int sl = 0; sl < 2; ++sl)
#pragma unroll
                    for (int jj = 0; jj < 2; ++jj)
#pragma unroll
                        for (int kh = 0; kh < 2; ++kh)
                            afr[sl][jj][kh] = ds_read8(ab + aoff[sl * 2 + jj][kh]);
            } else if (p < 3) {
#pragma unroll
                for (int jj = 0; jj < 2; ++jj)
#pragma unroll
                    for (int kh = 0; kh < 2; ++kh)
                        afr[(p + 1) & 1][jj][kh] =
                            ds_read8(ab + aoff[(p + 1) * 2 + jj][kh]);
            }
            // ---- stage next tile ----
            if (st) {
                if (p == 0)      { stA(nb, 0, k1); stA(nb, 2, k1); }
                else if (p == 1) { stB(nb, 0, k1); stB(nb, 1, k1); }
                else if (p == 2) { stB(nb, 2, k1); stB(nb, 3, k1); }
                else             { stA(nb, 1, k1); stA(nb, 3, k1); }
            }
            // ---- counted lgkm wait for the frags THIS phase consumes ----
            if (p == 3) wlg<0>(); else wlg<4>();
            SCHED0;
            __builtin_amdgcn_s_setprio(1);
#pragma unroll
            for (int kh = 0; kh < 2; ++kh)
#pragma unroll
                for (int jj = 0; jj < 2; ++jj)
#pragma unroll
                    for (int ni = 0; ni < 4; ++ni)
                        acc[2 * p + jj][ni] = __builtin_amdgcn_mfma_f32_16x16x32_bf16(
                            bres[ni][kh], afr[p & 1][jj][kh], acc[2 * p + jj][ni], 0, 0, 0);
            __builtin_amdgcn_s_setprio(0);
            SCHED0;
            // ---- counted vmcnt (R11 ledger) ----
            if (p == 0) {
                if (st) wvm<2>(); else wvm<0>();
            }
            if (p == 3 && st) wvm<2>();
            BARRIER; SCHED0;
        }
    }

    // epilogue: bf16 + bias + relu
    const int mbase = bm * 256 + wm * 128;
    const int nbase = bn * 256 + wn * 64;
#pragma unroll
    for (int mi = 0; mi < 8; ++mi) {
        const int m = mbase + mi * 16 + l16;
#pragma unroll
        for (int ni = 0; ni < 4; ++ni) {
            const int n0 = nbase + ni * 16 + quad * 4;
            const float4 bv = *(const float4*)&bias[n0];
            float v0 = fmaxf(acc[mi][ni][0] + bv.x, 0.f);
            float v1 = fmaxf(acc[mi][ni][1] + bv.y, 0.f);
            float v2 = fmaxf(acc[mi][ni][2] + bv.z, 0.f);
            float v3 = fmaxf(acc[mi][ni][3] + bv.w, 0.f);
            ushort4 o = { f2bf(v0), f2bf(v1), f2bf(v2), f2bf(v3) };
            *(ushort4*)&H[(size_t)m * N + n0] = o;
        }
    }
}

// ---------------------------------------------------------------------------
// R20 GEMM2 (= R11 gemm2 verbatim, proven; bm-fastest map):
// out = H @ W2t^T + b2, fp32. M=8192 N=1024 K=4096. BM=256 BN=128, grid
// 256 = 1/CU, 8 waves (4M x 2N), wave 64x64. Triple-buffered kh-split LDS;
// cross-tile frag read-ahead; staging 2 tiles ahead; uniform
// vmcnt(6)/lgkmcnt(8); one barrier per phase.
// ---------------------------------------------------------------------------
__global__ __launch_bounds__(512, 2)
void gemm2(const u16* __restrict__ A, const u16* __restrict__ Bt,
           const float* __restrict__ bias, float* __restrict__ Cout)
{
    constexpr int K = 4096, N = 1024;
    constexpr int ASZ = 2 * 256 * 32;    // u16 per buffer (32KB)
    constexpr int BSZ = 2 * 128 * 32;    // u16 per buffer (16KB)
    __shared__ __align__(16) u16 Alds[3 * ASZ];   // 96KB
    __shared__ __align__(16) u16 Blds[3 * BSZ];   // 48KB

    const int tid  = threadIdx.x;
    const int wave = tid >> 6;
    const int lane = tid & 63;
    const int quad = lane >> 4;
    const int l16  = lane & 15;
    const int key4 = (l16 >> 1) & 3;
    const int wm   = wave >> 1;          // 0..3
    const int wn   = wave & 1;           // 0..1

    const int id = blockIdx.x;
    const int bm = id & 31;              // bm-fastest (XCD-optimal)
    const int bn = id >> 5;

    const u16* Ag = A  + (size_t)bm * 256 * K;
    const u16* Bg = Bt + (size_t)bn * 128 * K;

    auto stA = [&](int buf, int kh, int c, int k0) {
        const int row = c * 128 + wave * 16 + (lane >> 2);
        const int col = kh * 32 + ((lane & 3) ^ ((row >> 1) & 3)) * 8;
        __builtin_amdgcn_global_load_lds(
            (AS1 void*)(Ag + (size_t)row * K + k0 + col),
            (AS3 void*)(&Alds[buf * ASZ + kh * 8192 + c * 4096 + wave * 512]),
            16, 0, 0);
    };
    auto stB = [&](int buf, int kh, int k0) {
        const int row = wave * 16 + (lane >> 2);
        const int col = kh * 32 + ((lane & 3) ^ ((row >> 1) & 3)) * 8;
        __builtin_amdgcn_global_load_lds(
            (AS1 void*)(Bg + (size_t)row * K + k0 + col),
            (AS3 void*)(&Blds[buf * BSZ + kh * 4096 + wave * 512]), 16, 0, 0);
    };

    const unsigned Ab = lds_off(&Alds[0]);
    const unsigned Bb = lds_off(&Blds[0]);
    unsigned aoff[4], boff[4];
#pragma unroll
    for (int mi = 0; mi < 4; ++mi)
        aoff[mi] = ((wm * 64 + mi * 16 + l16) * 32 + (quad ^ key4) * 8) * 2;
#pragma unroll
    for (int ni = 0; ni < 4; ++ni)
        boff[ni] = ((wn * 64 + ni * 16 + l16) * 32 + (quad ^ key4) * 8) * 2;

    floatx4 acc[4][4];
#pragma unroll
    for (int i = 0; i < 4; ++i)
#pragma unroll
        for (int j = 0; j < 4; ++j)
            acc[i][j] = (floatx4){0.f, 0.f, 0.f, 0.f};

    constexpr int NT = K / 64;           // 64

    stA(0, 0, 0, 0);  stA(0, 0, 1, 0);  stB(0, 0, 0);
    stA(0, 1, 0, 0);  stA(0, 1, 1, 0);  stB(0, 1, 0);
    stA(1, 0, 0, 64); stA(1, 0, 1, 64); stB(1, 0, 64);
    stA(1, 1, 0, 64); stA(1, 1, 1, 64); stB(1, 1, 64);
    wvm<6>();
    SCHED0; BARRIER; SCHED0;

    bf16x8 fa[2][4], fb[2][4];
#pragma unroll
    for (int i = 0; i < 4; ++i) {
        fa[0][i] = ds_read8(Ab + aoff[i]);
        fb[0][i] = ds_read8(Bb + boff[i]);
    }

    int bs0 = 0, bs1 = 1, bs2 = 2;
    for (int t = 0; t < NT; ++t) {
        const int k2 = (t + 2) * 64;
        const bool st  = (t + 2 < NT);
        const bool rd1 = (t + 1 < NT);
        const unsigned a0 = Ab + (unsigned)(bs0 * ASZ * 2);
        const unsigned b0 = Bb + (unsigned)(bs0 * BSZ * 2);
        const unsigned a1 = Ab + (unsigned)(bs1 * ASZ * 2);
        const unsigned b1 = Bb + (unsigned)(bs1 * BSZ * 2);

        // phase kh=0
#pragma unroll
        for (int i = 0; i < 4; ++i) {
            fa[1][i] = ds_read8(a0 + 16384u + aoff[i]);
            fb[1][i] = ds_read8(b0 + 8192u  + boff[i]);
        }
        if (st) { stA(bs2, 0, 0, k2); stA(bs2, 0, 1, k2); stB(bs2, 0, k2); }
        wlg<8>();
        SCHED0;
        __builtin_amdgcn_s_setprio(1);
#pragma unroll
        for (int mi = 0; mi < 4; ++mi)
#pragma unroll
            for (int ni = 0; ni < 4; ++ni)
                acc[mi][ni] = __builtin_amdgcn_mfma_f32_16x16x32_bf16(
                    fb[0][ni], fa[0][mi], acc[mi][ni], 0, 0, 0);
        __builtin_amdgcn_s_setprio(0);
        SCHED0;
        if (st)       wvm<6>();
        else if (rd1) wvm<3>();
        BARRIER; SCHED0;

        // phase kh=1
        if (rd1) {
#pragma unroll
            for (int i = 0; i < 4; ++i) {
                fa[0][i] = ds_read8(a1 + aoff[i]);
                fb[0][i] = ds_read8(b1 + boff[i]);
            }
        }
        if (st) { stA(bs2, 1, 0, k2); stA(bs2, 1, 1, k2); stB(bs2, 1, k2); }
        if (rd1) wlg<8>(); else wlg<0>();
        SCHED0;
        __builtin_amdgcn_s_setprio(1);
#pragma unroll
        for (int mi = 0; mi < 4; ++mi)
#pragma unroll
            for (int ni = 0; ni < 4; ++ni)
                acc[mi][ni] = __builtin_amdgcn_mfma_f32_16x16x32_bf16(
                    fb[1][ni], fa[1][mi], acc[mi][ni], 0, 0, 0);
        __builtin_amdgcn_s_setprio(0);
        SCHED0;
        if (st)       wvm<6>();
        else if (rd1) wvm<0>();
        BARRIER; SCHED0;

        const int tmp = bs0; bs0 = bs1; bs1 = bs2; bs2 = tmp;
    }

    const int mbase = bm * 256 + wm * 64;
    const int nbase = bn * 128 + wn * 64;
#pragma unroll
    for (int mi = 0; mi < 4; ++mi) {
        const int m = mbase + mi * 16 + l16;
#pragma unroll
        for (int ni = 0; ni < 4; ++ni) {
            const int n0 = nbase + ni * 16 + quad * 4;
            const float4 bv = *(const float4*)&bias[n0];
            float4 o = { acc[mi][ni][0] + bv.x, acc[mi][ni][1] + bv.y,
                         acc[mi][ni][2] + bv.z, acc[mi][ni][3] + bv.w };
            *(float4*)&Cout[(size_t)m * N + n0] = o;
        }
    }
}

// ---------------------------------------------------------------------------
// inputs: 0 act(4,2048,1024) f32, 1 mask(unused), 2 ln_scale(1024),
//         3 ln_bias(1024), 4 w1(1024,4096), 5 b1(4096), 6 w2(4096,1024),
//         7 b2(1024). out: (4,2048,1024) f32.
// ws (bf16 bits): X[8192*1024] | W1t[4096*1024] | W2t[1024*4096] | H[8192*4096]
// ---------------------------------------------------------------------------
extern "C" void kernel_launch(void* const* d_in, const int* in_sizes, int n_in,
                              void* d_out, int out_size, void* d_ws, size_t ws_size,
                              hipStream_t stream)
{
    const float* act      = (const float*)d_in[0];
    const float* ln_scale = (const float*)d_in[2];
    const float* ln_bias  = (const float*)d_in[3];
    const float* w1       = (const float*)d_in[4];
    const float* b1       = (const float*)d_in[5];
    const float* w2       = (const float*)d_in[6];
    const float* b2       = (const float*)d_in[7];
    float* out = (float*)d_out;

    const int M = 8192, C = 1024, CI = 4096;

    u16* X   = (u16*)d_ws;                 // [M][C]
    u16* W1t = X   + (size_t)M * C;        // [CI][C]
    u16* W2t = W1t + (size_t)CI * C;       // [C][CI]
    u16* H   = W2t + (size_t)C * CI;       // [M][CI]

    // prep: balanced 128x64 transposes + wave-per-row LN (fixed coverage)
    prep<<<3072, 256, 0, stream>>>(w1, w2, act, ln_scale, ln_bias, W1t, W2t, X);
    // H = relu(X @ W1 + b1): R11 schedule, bm-fastest map
    gemm1<<<(M / 256) * (CI / 256), 512, 0, stream>>>(X, W1t, b1, H);
    // out = H @ W2 + b2: R11 schedule, bm-fastest map
    gemm2<<<(M / 256) * (C / 128), 512, 0, stream>>>(H, W2t, b2, out);
}